// Round 1
// baseline (394.785 us; speedup 1.0000x reference)
//
#include <hip/hip_runtime.h>

#define Bdim 2
#define Tdim 2048
#define Edim 1024
#define Hdim 16
#define Sdim 64
#define Mdim 4096
#define LN_EPS 1e-5f
#define INV4 0.17677669529663687f   // 1024^-0.25

typedef __bf16 bf16x8 __attribute__((ext_vector_type(8)));
typedef float f32x4 __attribute__((ext_vector_type(4)));
typedef unsigned short ushort8 __attribute__((ext_vector_type(8)));

__device__ __forceinline__ unsigned short f2bf(float f) {
  union { float f; unsigned int u; } c; c.f = f;
  unsigned int u = c.u;
  unsigned int r = (u + 0x7FFFu + ((u >> 16) & 1u)) >> 16;
  return (unsigned short)r;
}

// ---------------------------------------------------------------------------
// Transpose + convert W [K][N] fp32 -> Wt [N][K] bf16 (4 matrices via grid.z)
// ---------------------------------------------------------------------------
__global__ __launch_bounds__(256) void wconv_k(
    const float* __restrict__ W0, const float* __restrict__ W1,
    const float* __restrict__ W2, const float* __restrict__ W3,
    unsigned short* __restrict__ O0, unsigned short* __restrict__ O1,
    unsigned short* __restrict__ O2, unsigned short* __restrict__ O3) {
  const float* W = blockIdx.z == 0 ? W0 : blockIdx.z == 1 ? W1 : blockIdx.z == 2 ? W2 : W3;
  unsigned short* O = blockIdx.z == 0 ? O0 : blockIdx.z == 1 ? O1 : blockIdx.z == 2 ? O2 : O3;
  __shared__ float tile[32][33];
  int n0 = blockIdx.x * 32, k0 = blockIdx.y * 32;
  int tx = threadIdx.x, ty = threadIdx.y; // block (32,8)
  for (int yy = ty; yy < 32; yy += 8)
    tile[yy][tx] = W[(size_t)(k0 + yy) * Edim + n0 + tx];
  __syncthreads();
  for (int yy = ty; yy < 32; yy += 8)
    O[(size_t)(n0 + yy) * Edim + k0 + tx] = f2bf(tile[tx][yy]);
}

// ---------------------------------------------------------------------------
// GEMM: Y[M][N] = A[M][K] * Bt[N][K]^T   (128x128 tile, 4 waves, BK=32)
// EPI==1: per-head LayerNorm + *INV4 -> bf16 [B,H,T,S]
// EPI==2: plain -> bf16 [B,H,T,S]
// EPI==3: A is bf16, +bias -> fp32 [M][N]
// ---------------------------------------------------------------------------
template <int EPI>
__global__ __launch_bounds__(256) void gemm_k(
    const float* __restrict__ Afp, const unsigned short* __restrict__ Abf,
    const unsigned short* __restrict__ Bt,
    const float* __restrict__ lnw, const float* __restrict__ lnb,
    const float* __restrict__ bias,
    unsigned short* __restrict__ obf, float* __restrict__ ofp) {
  const int LDK = 56;  // 32 + 24 pad: 112B row stride, 16B aligned, conflict-free
  __shared__ unsigned short As[128 * LDK];
  __shared__ unsigned short Bs[128 * LDK];
  int tid = threadIdx.x, lane = tid & 63, w = tid >> 6;
  int wr = w >> 1, wc = w & 1;
  int lg = lane >> 4, l15 = lane & 15;
  int m0 = blockIdx.y * 128, n0 = blockIdx.x * 128;

  f32x4 zero = {0.f, 0.f, 0.f, 0.f};
  f32x4 acc[4][4];
#pragma unroll
  for (int i = 0; i < 4; ++i)
#pragma unroll
    for (int j = 0; j < 4; ++j) acc[i][j] = zero;

  for (int k0 = 0; k0 < Edim; k0 += 32) {
    __syncthreads();
    if (EPI == 3) {
#pragma unroll
      for (int it = 0; it < 2; ++it) {
        int c = tid + it * 256;
        int row = c >> 2, kc = (c & 3) * 8;
        *(int4*)&As[row * LDK + kc] =
            *(const int4*)&Abf[(size_t)(m0 + row) * Edim + k0 + kc];
      }
    } else {
#pragma unroll
      for (int it = 0; it < 4; ++it) {
        int c = tid + it * 256;
        int row = c >> 3, kc = (c & 7) * 4;
        float4 v = *(const float4*)&Afp[(size_t)(m0 + row) * Edim + k0 + kc];
        ushort4 o;
        o.x = f2bf(v.x); o.y = f2bf(v.y); o.z = f2bf(v.z); o.w = f2bf(v.w);
        *(ushort4*)&As[row * LDK + kc] = o;
      }
    }
#pragma unroll
    for (int it = 0; it < 2; ++it) {
      int c = tid + it * 256;
      int row = c >> 2, kc = (c & 3) * 8;
      *(int4*)&Bs[row * LDK + kc] =
          *(const int4*)&Bt[(size_t)(n0 + row) * Edim + k0 + kc];
    }
    __syncthreads();

    bf16x8 a[4], b[4];
#pragma unroll
    for (int i = 0; i < 4; ++i)
      a[i] = *(const bf16x8*)&As[(wr * 64 + i * 16 + l15) * LDK + lg * 8];
#pragma unroll
    for (int j = 0; j < 4; ++j)
      b[j] = *(const bf16x8*)&Bs[(wc * 64 + j * 16 + l15) * LDK + lg * 8];
#pragma unroll
    for (int i = 0; i < 4; ++i)
#pragma unroll
      for (int j = 0; j < 4; ++j)
        acc[i][j] = __builtin_amdgcn_mfma_f32_16x16x32_bf16(a[i], b[j], acc[i][j], 0, 0, 0);
  }

  int mb = m0 + wr * 64, nb = n0 + wc * 64;
  if (EPI == 1 || EPI == 2) {
    int h = nb >> 6;  // wave's 64 cols == exactly one head
#pragma unroll
    for (int i = 0; i < 4; ++i) {
#pragma unroll
      for (int r = 0; r < 4; ++r) {
        float x[4];
#pragma unroll
        for (int j = 0; j < 4; ++j) x[j] = acc[i][j][r];
        float outv[4];
        if (EPI == 1) {
          float sum = x[0] + x[1] + x[2] + x[3];
          float sq = x[0] * x[0] + x[1] * x[1] + x[2] * x[2] + x[3] * x[3];
#pragma unroll
          for (int off = 1; off < 16; off <<= 1) {
            sum += __shfl_xor(sum, off);
            sq += __shfl_xor(sq, off);
          }
          float mean = sum * (1.f / 64.f);
          float var = sq * (1.f / 64.f) - mean * mean;
          float rstd = rsqrtf(var + LN_EPS);
#pragma unroll
          for (int j = 0; j < 4; ++j) {
            int s = j * 16 + l15;
            outv[j] = ((x[j] - mean) * rstd * lnw[s] + lnb[s]) * INV4;
          }
        } else {
#pragma unroll
          for (int j = 0; j < 4; ++j) outv[j] = x[j];
        }
        int m = mb + i * 16 + (lg << 2) + r;
        int bb = m >> 11, tt = m & 2047;
        size_t base = ((size_t)(bb * Hdim + h) * Tdim + tt) * Sdim;
#pragma unroll
        for (int j = 0; j < 4; ++j) obf[base + j * 16 + l15] = f2bf(outv[j]);
      }
    }
  } else {  // EPI == 3
#pragma unroll
    for (int i = 0; i < 4; ++i)
#pragma unroll
      for (int r = 0; r < 4; ++r) {
        int m = mb + i * 16 + (lg << 2) + r;
#pragma unroll
        for (int j = 0; j < 4; ++j) {
          int n = nb + j * 16 + l15;
          ofp[(size_t)m * Edim + n] = acc[i][j][r] + bias[n];
        }
      }
  }
}

// ---------------------------------------------------------------------------
// Flash attention: grid (qb=T/64, bh=B*H). 4 waves, QBLK=64, KV tiles of 64.
// ---------------------------------------------------------------------------
__global__ __launch_bounds__(256) void flash_k(
    const unsigned short* __restrict__ Qn, const unsigned short* __restrict__ Kn,
    const unsigned short* __restrict__ Vb, unsigned short* __restrict__ Ob) {
  const int LDP = 72;  // 144B stride: 16B aligned, conflict-free
  __shared__ unsigned short Qs[64 * LDP];
  __shared__ unsigned short Ks[64 * LDP];
  __shared__ unsigned short Vt[64 * LDP];  // transposed: Vt[s][kv]
  __shared__ unsigned short Ps[4][16 * LDP];
  int qb = blockIdx.x, bh = blockIdx.y;
  int tid = threadIdx.x, lane = tid & 63, w = tid >> 6;
  int lg = lane >> 4, l15 = lane & 15;
  const unsigned short* Qg = Qn + (size_t)bh * Tdim * Sdim;
  const unsigned short* Kg = Kn + (size_t)bh * Tdim * Sdim;
  const unsigned short* Vg = Vb + (size_t)bh * Tdim * Sdim;

#pragma unroll
  for (int it = 0; it < 2; ++it) {
    int c = tid + it * 256;
    int row = c >> 3, s0 = (c & 7) * 8;
    *(int4*)&Qs[row * LDP + s0] = *(const int4*)&Qg[(size_t)(qb * 64 + row) * Sdim + s0];
  }

  f32x4 zero = {0.f, 0.f, 0.f, 0.f};
  float mrun[4], lrun[4];
  f32x4 o[4];
#pragma unroll
  for (int r = 0; r < 4; ++r) { mrun[r] = -1e30f; lrun[r] = 0.f; }
#pragma unroll
  for (int js = 0; js < 4; ++js) o[js] = zero;

  for (int t = 0; t <= qb; ++t) {
    __syncthreads();
#pragma unroll
    for (int it = 0; it < 2; ++it) {
      int c = tid + it * 256;
      int row = c >> 3, s0 = (c & 7) * 8;
      *(int4*)&Ks[row * LDP + s0] = *(const int4*)&Kg[(size_t)(t * 64 + row) * Sdim + s0];
    }
#pragma unroll
    for (int it = 0; it < 2; ++it) {
      int c = tid + it * 256;
      int kv = c & 63, s0 = (c >> 6) * 8;
      ushort8 v = *(const ushort8*)&Vg[(size_t)(t * 64 + kv) * Sdim + s0];
#pragma unroll
      for (int jj = 0; jj < 8; ++jj) Vt[(s0 + jj) * LDP + kv] = v[jj];
    }
    __syncthreads();

    // scores S = Q Kt : wave w owns q-rows w*16..w*16+15, all 64 kv cols
    f32x4 sf[4];
#pragma unroll
    for (int j = 0; j < 4; ++j) sf[j] = zero;
#pragma unroll
    for (int kk = 0; kk < 64; kk += 32) {
      bf16x8 aq = *(const bf16x8*)&Qs[(w * 16 + l15) * LDP + kk + lg * 8];
#pragma unroll
      for (int j = 0; j < 4; ++j) {
        bf16x8 bk = *(const bf16x8*)&Ks[(j * 16 + l15) * LDP + kk + lg * 8];
        sf[j] = __builtin_amdgcn_mfma_f32_16x16x32_bf16(aq, bk, sf[j], 0, 0, 0);
      }
    }
    if (t == qb) {
#pragma unroll
      for (int j = 0; j < 4; ++j)
#pragma unroll
        for (int r = 0; r < 4; ++r) {
          int col = j * 16 + l15, rowq = w * 16 + (lg << 2) + r;
          if (col > rowq) sf[j][r] = -1e30f;
        }
    }
    // online softmax per reg-row (stats replicated across 16-lane group)
#pragma unroll
    for (int r = 0; r < 4; ++r) {
      float mx = fmaxf(fmaxf(sf[0][r], sf[1][r]), fmaxf(sf[2][r], sf[3][r]));
#pragma unroll
      for (int off = 1; off < 16; off <<= 1) mx = fmaxf(mx, __shfl_xor(mx, off));
      float mnew = fmaxf(mrun[r], mx);
      float alpha = __expf(mrun[r] - mnew);
      float p[4], ps = 0.f;
#pragma unroll
      for (int j = 0; j < 4; ++j) { p[j] = __expf(sf[j][r] - mnew); ps += p[j]; }
#pragma unroll
      for (int off = 1; off < 16; off <<= 1) ps += __shfl_xor(ps, off);
      lrun[r] = lrun[r] * alpha + ps;
      mrun[r] = mnew;
#pragma unroll
      for (int js = 0; js < 4; ++js) o[js][r] *= alpha;
#pragma unroll
      for (int j = 0; j < 4; ++j)
        Ps[w][((lg << 2) + r) * LDP + j * 16 + l15] = f2bf(p[j]);
    }
    // PV: O += P * V
#pragma unroll
    for (int kk = 0; kk < 64; kk += 32) {
      bf16x8 ap = *(const bf16x8*)&Ps[w][l15 * LDP + kk + lg * 8];
#pragma unroll
      for (int js = 0; js < 4; ++js) {
        bf16x8 bv = *(const bf16x8*)&Vt[(js * 16 + l15) * LDP + kk + lg * 8];
        o[js] = __builtin_amdgcn_mfma_f32_16x16x32_bf16(ap, bv, o[js], 0, 0, 0);
      }
    }
  }

  int b = bh >> 4, h = bh & 15;
#pragma unroll
  for (int r = 0; r < 4; ++r) {
    float inv = 1.f / lrun[r];
    int tg = qb * 64 + w * 16 + (lg << 2) + r;
    size_t base = ((size_t)(b * Tdim + tg)) * Edim + h * 64;
#pragma unroll
    for (int js = 0; js < 4; ++js) Ob[base + js * 16 + l15] = f2bf(o[js][r] * inv);
  }
}

// ---------------------------------------------------------------------------
extern "C" void kernel_launch(void* const* d_in, const int* in_sizes, int n_in,
                              void* d_out, int out_size, void* d_ws, size_t ws_size,
                              hipStream_t stream) {
  const float* queries = (const float*)d_in[0];
  const float* keys    = (const float*)d_in[1];
  const float* values  = (const float*)d_in[2];
  const float* Wq = (const float*)d_in[3];
  const float* Wk = (const float*)d_in[4];
  const float* Wv = (const float*)d_in[5];
  const float* Wo = (const float*)d_in[6];
  const float* bo = (const float*)d_in[7];
  const float* qlnw = (const float*)d_in[8];
  const float* qlnb = (const float*)d_in[9];
  const float* klnw = (const float*)d_in[10];
  const float* klnb = (const float*)d_in[11];
  float* out = (float*)d_out;

  unsigned short* Wtq = (unsigned short*)d_ws;
  unsigned short* Wtk = Wtq + 1024 * 1024;
  unsigned short* Wtv = Wtk + 1024 * 1024;
  unsigned short* Wto = Wtv + 1024 * 1024;
  unsigned short* Qn  = Wto + 1024 * 1024;
  unsigned short* Kn  = Qn + (size_t)Mdim * Edim;
  unsigned short* Vb  = Kn + (size_t)Mdim * Edim;
  unsigned short* Ob  = Vb + (size_t)Mdim * Edim;

  wconv_k<<<dim3(32, 32, 4), dim3(32, 8), 0, stream>>>(Wq, Wk, Wv, Wo, Wtq, Wtk, Wtv, Wto);
  gemm_k<1><<<dim3(8, 32), 256, 0, stream>>>(queries, nullptr, Wtq, qlnw, qlnb, nullptr, Qn, nullptr);
  gemm_k<1><<<dim3(8, 32), 256, 0, stream>>>(keys, nullptr, Wtk, klnw, klnb, nullptr, Kn, nullptr);
  gemm_k<2><<<dim3(8, 32), 256, 0, stream>>>(values, nullptr, Wtv, nullptr, nullptr, nullptr, Vb, nullptr);
  flash_k<<<dim3(32, 32), 256, 0, stream>>>(Qn, Kn, Vb, Ob);
  gemm_k<3><<<dim3(8, 32), 256, 0, stream>>>(nullptr, Ob, Wto, nullptr, nullptr, bo, nullptr, out);
}

// Round 2
// 303.659 us; speedup vs baseline: 1.3001x; 1.3001x over previous
//
#include <hip/hip_runtime.h>

#define Tdim 2048
#define Edim 1024
#define Hdim 16
#define Sdim 64
#define Mdim 4096
#define LN_EPS 1e-5f
#define INV4 0.17677669529663687f   // 1024^-0.25

typedef __bf16 bf16x8 __attribute__((ext_vector_type(8)));
typedef float f32x4 __attribute__((ext_vector_type(4)));
typedef unsigned short ushortx8 __attribute__((ext_vector_type(8)));

__device__ __forceinline__ unsigned short f2bf(float f) {
  union { float f; unsigned int u; } c; c.f = f;
  unsigned int u = c.u;
  return (unsigned short)((u + 0x7FFFu + ((u >> 16) & 1u)) >> 16);
}

// async global->LDS, 16B per lane, lane-contiguous at LDS base
__device__ __forceinline__ void gl_lds16(const void* g, void* l) {
  __builtin_amdgcn_global_load_lds(
      (const __attribute__((address_space(1))) void*)g,
      (__attribute__((address_space(3))) void*)l, 16, 0, 0);
}

// pack two fp32 (as bits) -> dword of two bf16 (truncate): [bf(hi)<<16 | bf(lo)]
__device__ __forceinline__ unsigned int pk2bf(unsigned int lo, unsigned int hi) {
  return __builtin_amdgcn_perm(hi, lo, 0x07060302u);
}

// ---------------------------------------------------------------------------
// Transpose + convert W [K][N] fp32 -> Wt [N][K] bf16 (4 matrices via grid.z)
// ---------------------------------------------------------------------------
__global__ __launch_bounds__(256) void wconv_k(
    const float* __restrict__ W0, const float* __restrict__ W1,
    const float* __restrict__ W2, const float* __restrict__ W3,
    unsigned short* __restrict__ O0, unsigned short* __restrict__ O1,
    unsigned short* __restrict__ O2, unsigned short* __restrict__ O3) {
  const float* W = blockIdx.z == 0 ? W0 : blockIdx.z == 1 ? W1 : blockIdx.z == 2 ? W2 : W3;
  unsigned short* O = blockIdx.z == 0 ? O0 : blockIdx.z == 1 ? O1 : blockIdx.z == 2 ? O2 : O3;
  __shared__ float tile[32][33];
  int n0 = blockIdx.x * 32, k0 = blockIdx.y * 32;
  int tx = threadIdx.x, ty = threadIdx.y; // block (32,8)
  for (int yy = ty; yy < 32; yy += 8)
    tile[yy][tx] = W[(size_t)(k0 + yy) * Edim + n0 + tx];
  __syncthreads();
  for (int yy = ty; yy < 32; yy += 8)
    O[(size_t)(n0 + yy) * Edim + k0 + tx] = f2bf(tile[tx][yy]);
}

// ---------------------------------------------------------------------------
// Fused QKV GEMM: z selects {queries,keys,values}. 128x128 tile, BK=64,
// 4 waves (2x2), XOR-swizzled LDS. B via global_load_lds; A fp32->bf16 packed.
// Epilogue: per-head LayerNorm (+INV4) for z<2, plain for z==2 -> bf16 [B,H,T,S]
// ---------------------------------------------------------------------------
__global__ __launch_bounds__(256) void qkv_k(
    const float* __restrict__ Aq, const float* __restrict__ Ak, const float* __restrict__ Av,
    const unsigned short* __restrict__ Bq, const unsigned short* __restrict__ Bk,
    const unsigned short* __restrict__ Bv,
    const float* __restrict__ qlnw, const float* __restrict__ qlnb,
    const float* __restrict__ klnw, const float* __restrict__ klnb,
    unsigned short* __restrict__ Oq, unsigned short* __restrict__ Ok,
    unsigned short* __restrict__ Ov) {
  __shared__ unsigned short As[128 * 64];
  __shared__ unsigned short Bs[128 * 64];
  const int z = blockIdx.z;
  const float* A = z == 0 ? Aq : z == 1 ? Ak : Av;
  const unsigned short* Bt = z == 0 ? Bq : z == 1 ? Bk : Bv;
  const float* lnw = z == 0 ? qlnw : klnw;
  const float* lnb = z == 0 ? qlnb : klnb;
  unsigned short* obf = z == 0 ? Oq : z == 1 ? Ok : Ov;
  const bool doLN = z < 2;

  int tid = threadIdx.x, lane = tid & 63, w = tid >> 6;
  int wr = w >> 1, wc = w & 1;
  int lg = lane >> 4, l15 = lane & 15;
  int lr = lane >> 3, ls = lane & 7;
  int m0 = blockIdx.y * 128, n0 = blockIdx.x * 128;

  f32x4 acc[4][4];
#pragma unroll
  for (int i = 0; i < 4; ++i)
#pragma unroll
    for (int j = 0; j < 4; ++j) acc[i][j] = f32x4{0.f, 0.f, 0.f, 0.f};

  for (int k0 = 0; k0 < Edim; k0 += 64) {
    __syncthreads();
    // B tile (128x64 bf16 = 16KB = 16 chunks), pre-swizzled source
#pragma unroll
    for (int q = 0; q < 4; ++q) {
      int c = w * 4 + q;
      int r = c * 8 + lr;
      gl_lds16(&Bt[(size_t)(n0 + r) * Edim + k0 + ((ls ^ (r & 7)) * 8)], &Bs[c * 512]);
    }
    // A tile: fp32 -> bf16 truncate-pack, swizzled ds_write
#pragma unroll
    for (int p = 0; p < 4; ++p) {
      int seg = tid + p * 256;
      int r = seg >> 3, s = seg & 7;
      const float* src = &A[(size_t)(m0 + r) * Edim + k0 + s * 8];
      uint4 f0 = *(const uint4*)src;
      uint4 f1 = *(const uint4*)(src + 4);
      uint4 o;
      o.x = pk2bf(f0.x, f0.y);
      o.y = pk2bf(f0.z, f0.w);
      o.z = pk2bf(f1.x, f1.y);
      o.w = pk2bf(f1.z, f1.w);
      *(uint4*)&As[r * 64 + ((s ^ (r & 7)) * 8)] = o;
    }
    __syncthreads();
#pragma unroll
    for (int kx = 0; kx < 2; ++kx) {
      bf16x8 a[4], b[4];
#pragma unroll
      for (int i = 0; i < 4; ++i) {
        int r = wr * 64 + i * 16 + l15;
        a[i] = *(const bf16x8*)&As[r * 64 + (((kx * 4 + lg) ^ (r & 7)) * 8)];
      }
#pragma unroll
      for (int j = 0; j < 4; ++j) {
        int r = wc * 64 + j * 16 + l15;
        b[j] = *(const bf16x8*)&Bs[r * 64 + (((kx * 4 + lg) ^ (r & 7)) * 8)];
      }
#pragma unroll
      for (int i = 0; i < 4; ++i)
#pragma unroll
        for (int j = 0; j < 4; ++j)
          acc[i][j] = __builtin_amdgcn_mfma_f32_16x16x32_bf16(a[i], b[j], acc[i][j], 0, 0, 0);
    }
  }

  int mb = m0 + wr * 64;
  int h = (n0 >> 6) + wc;  // wave's 64 cols == one head
#pragma unroll
  for (int i = 0; i < 4; ++i) {
#pragma unroll
    for (int r = 0; r < 4; ++r) {
      float x[4];
#pragma unroll
      for (int j = 0; j < 4; ++j) x[j] = acc[i][j][r];
      float outv[4];
      if (doLN) {
        float sum = x[0] + x[1] + x[2] + x[3];
        float sq = x[0] * x[0] + x[1] * x[1] + x[2] * x[2] + x[3] * x[3];
#pragma unroll
        for (int off = 1; off < 16; off <<= 1) {
          sum += __shfl_xor(sum, off);
          sq += __shfl_xor(sq, off);
        }
        float mean = sum * (1.f / 64.f);
        float var = sq * (1.f / 64.f) - mean * mean;
        float rstd = rsqrtf(var + LN_EPS);
#pragma unroll
        for (int j = 0; j < 4; ++j) {
          int s = j * 16 + l15;
          outv[j] = ((x[j] - mean) * rstd * lnw[s] + lnb[s]) * INV4;
        }
      } else {
#pragma unroll
        for (int j = 0; j < 4; ++j) outv[j] = x[j];
      }
      int m = mb + i * 16 + (lg << 2) + r;
      int bb = m >> 11, tt = m & 2047;
      size_t base = ((size_t)(bb * Hdim + h) * Tdim + tt) * Sdim;
#pragma unroll
      for (int j = 0; j < 4; ++j) obf[base + j * 16 + l15] = f2bf(outv[j]);
    }
  }
}

// ---------------------------------------------------------------------------
// Out-projection GEMM: Y = Ob(bf16) * Wto^T + bo -> fp32. 128x64 tile, BK=64.
// ---------------------------------------------------------------------------
__global__ __launch_bounds__(256) void gemmo_k(
    const unsigned short* __restrict__ A, const unsigned short* __restrict__ Bt,
    const float* __restrict__ bias, float* __restrict__ ofp) {
  __shared__ unsigned short As[128 * 64];
  __shared__ unsigned short Bs[64 * 64];
  int tid = threadIdx.x, lane = tid & 63, w = tid >> 6;
  int wr = w >> 1, wc = w & 1;
  int lg = lane >> 4, l15 = lane & 15;
  int lr = lane >> 3, ls = lane & 7;
  int m0 = blockIdx.y * 128, n0 = blockIdx.x * 64;

  f32x4 acc[4][2];
#pragma unroll
  for (int i = 0; i < 4; ++i)
#pragma unroll
    for (int j = 0; j < 2; ++j) acc[i][j] = f32x4{0.f, 0.f, 0.f, 0.f};

  for (int k0 = 0; k0 < Edim; k0 += 64) {
    __syncthreads();
#pragma unroll
    for (int q = 0; q < 4; ++q) {
      int c = w * 4 + q;
      int r = c * 8 + lr;
      gl_lds16(&A[(size_t)(m0 + r) * Edim + k0 + ((ls ^ (r & 7)) * 8)], &As[c * 512]);
    }
#pragma unroll
    for (int q = 0; q < 2; ++q) {
      int c = w * 2 + q;
      int r = c * 8 + lr;
      gl_lds16(&Bt[(size_t)(n0 + r) * Edim + k0 + ((ls ^ (r & 7)) * 8)], &Bs[c * 512]);
    }
    __syncthreads();
#pragma unroll
    for (int kx = 0; kx < 2; ++kx) {
      bf16x8 a[4], b[2];
#pragma unroll
      for (int i = 0; i < 4; ++i) {
        int r = wr * 64 + i * 16 + l15;
        a[i] = *(const bf16x8*)&As[r * 64 + (((kx * 4 + lg) ^ (r & 7)) * 8)];
      }
#pragma unroll
      for (int j = 0; j < 2; ++j) {
        int r = wc * 32 + j * 16 + l15;
        b[j] = *(const bf16x8*)&Bs[r * 64 + (((kx * 4 + lg) ^ (r & 7)) * 8)];
      }
#pragma unroll
      for (int i = 0; i < 4; ++i)
#pragma unroll
        for (int j = 0; j < 2; ++j)
          acc[i][j] = __builtin_amdgcn_mfma_f32_16x16x32_bf16(a[i], b[j], acc[i][j], 0, 0, 0);
    }
  }

  int mb = m0 + wr * 64, nb = n0 + wc * 32;
#pragma unroll
  for (int i = 0; i < 4; ++i)
#pragma unroll
    for (int r = 0; r < 4; ++r) {
      int m = mb + i * 16 + (lg << 2) + r;
#pragma unroll
      for (int j = 0; j < 2; ++j) {
        int n = nb + j * 16 + l15;
        ofp[(size_t)m * Edim + n] = acc[i][j][r] + bias[n];
      }
    }
}

// ---------------------------------------------------------------------------
// Flash attention: QBLK=128 (4 waves x 32 rows), KVBLK=64, swizzled LDS,
// reg-prefetched K/V, static work-pairing for causal balance.
// ---------------------------------------------------------------------------
__global__ __launch_bounds__(256) void flash_k(
    const unsigned short* __restrict__ Qn, const unsigned short* __restrict__ Kn,
    const unsigned short* __restrict__ Vb, unsigned short* __restrict__ Ob) {
  __shared__ unsigned short Qs[128 * 64];
  __shared__ unsigned short Ks[64 * 64];
  __shared__ unsigned short Vt[64 * 64];     // [s][kv], swizzled
  __shared__ unsigned short Ps[4][32 * 64];  // per-wave P, swizzled
  // static balance: CU pairs block (x,y) with (x,y+16): qb sums to 15
  int x = blockIdx.x, y = blockIdx.y;
  int qb = (y >= 16) ? x : (15 - x);
  int bh = y;
  int tid = threadIdx.x, lane = tid & 63, w = tid >> 6;
  int lg = lane >> 4, l15 = lane & 15;
  int lr = lane >> 3, ls = lane & 7;
  const unsigned short* Qg = Qn + ((size_t)bh * Tdim + (size_t)qb * 128) * Sdim;
  const unsigned short* Kg = Kn + (size_t)bh * Tdim * Sdim;
  const unsigned short* Vg = Vb + (size_t)bh * Tdim * Sdim;

  // stage Q (16KB = 16 chunks), pre-swizzled source
#pragma unroll
  for (int q = 0; q < 4; ++q) {
    int c = w * 4 + q;
    int r = c * 8 + lr;
    gl_lds16(&Qg[r * 64 + ((ls ^ (r & 7)) * 8)], &Qs[c * 512]);
  }

  uint4 kreg[2];
  ushortx8 vreg[2];
  auto ldKV = [&](int t) {
    const unsigned short* Kt = Kg + (size_t)t * 64 * Sdim;
    const unsigned short* Vtg = Vg + (size_t)t * 64 * Sdim;
#pragma unroll
    for (int p = 0; p < 2; ++p) {
      int seg = tid + p * 256;
      kreg[p] = *(const uint4*)&Kt[(seg >> 3) * 64 + (seg & 7) * 8];
      vreg[p] = *(const ushortx8*)&Vtg[(seg & 63) * 64 + (seg >> 6) * 8];
    }
  };
  auto stKV = [&]() {
#pragma unroll
    for (int p = 0; p < 2; ++p) {
      int seg = tid + p * 256;
      int r = seg >> 3, s = seg & 7;
      *(uint4*)&Ks[r * 64 + ((s ^ (r & 7)) * 8)] = kreg[p];
      int kv = seg & 63, s0 = (seg >> 6) * 8;
#pragma unroll
      for (int jj = 0; jj < 8; ++jj) {
        int sr = s0 + jj;
        Vt[sr * 64 + (((kv >> 3) ^ (sr & 7)) * 8) + (kv & 7)] = vreg[p][jj];
      }
    }
  };

  float mrun[2][4], lrun[2][4];
  f32x4 o[2][4];
#pragma unroll
  for (int i = 0; i < 2; ++i)
#pragma unroll
    for (int r = 0; r < 4; ++r) { mrun[i][r] = -1e30f; lrun[i][r] = 0.f; }
#pragma unroll
  for (int i = 0; i < 2; ++i)
#pragma unroll
    for (int js = 0; js < 4; ++js) o[i][js] = f32x4{0.f, 0.f, 0.f, 0.f};

  ldKV(0);
  int nt = 2 * qb + 2;
  for (int t = 0; t < nt; ++t) {
    __syncthreads();          // previous tile's LDS reads done
    stKV();
    if (t + 1 < nt) ldKV(t + 1);  // prefetch overlaps compute below
    __syncthreads();

    // S = Q K^T : wave w owns q-rows w*32..w*32+31
    f32x4 sf[2][4];
#pragma unroll
    for (int i = 0; i < 2; ++i)
#pragma unroll
      for (int j = 0; j < 4; ++j) sf[i][j] = f32x4{0.f, 0.f, 0.f, 0.f};
#pragma unroll
    for (int kx = 0; kx < 2; ++kx) {
      bf16x8 aq[2];
#pragma unroll
      for (int i = 0; i < 2; ++i) {
        int r = w * 32 + i * 16 + l15;
        aq[i] = *(const bf16x8*)&Qs[r * 64 + (((kx * 4 + lg) ^ (r & 7)) * 8)];
      }
#pragma unroll
      for (int j = 0; j < 4; ++j) {
        int r = j * 16 + l15;
        bf16x8 bk = *(const bf16x8*)&Ks[r * 64 + (((kx * 4 + lg) ^ (r & 7)) * 8)];
#pragma unroll
        for (int i = 0; i < 2; ++i)
          sf[i][j] = __builtin_amdgcn_mfma_f32_16x16x32_bf16(aq[i], bk, sf[i][j], 0, 0, 0);
      }
    }
    if (t >= 2 * qb) {  // causal mask (only the last two tiles)
#pragma unroll
      for (int i = 0; i < 2; ++i)
#pragma unroll
        for (int j = 0; j < 4; ++j)
#pragma unroll
          for (int rr = 0; rr < 4; ++rr) {
            int col = t * 64 + j * 16 + l15;
            int row = qb * 128 + w * 32 + i * 16 + (lg << 2) + rr;
            if (col > row) sf[i][j][rr] = -1e30f;
          }
    }
    // online softmax per reg-row
#pragma unroll
    for (int i = 0; i < 2; ++i)
#pragma unroll
      for (int rr = 0; rr < 4; ++rr) {
        float mx = fmaxf(fmaxf(sf[i][0][rr], sf[i][1][rr]), fmaxf(sf[i][2][rr], sf[i][3][rr]));
#pragma unroll
        for (int off = 1; off < 16; off <<= 1) mx = fmaxf(mx, __shfl_xor(mx, off));
        float mnew = fmaxf(mrun[i][rr], mx);
        float alpha = __expf(mrun[i][rr] - mnew);
        float p[4], psum = 0.f;
#pragma unroll
        for (int j = 0; j < 4; ++j) { p[j] = __expf(sf[i][j][rr] - mnew); psum += p[j]; }
#pragma unroll
        for (int off = 1; off < 16; off <<= 1) psum += __shfl_xor(psum, off);
        lrun[i][rr] = lrun[i][rr] * alpha + psum;
        mrun[i][rr] = mnew;
#pragma unroll
        for (int js = 0; js < 4; ++js) o[i][js][rr] *= alpha;
        int qr = i * 16 + (lg << 2) + rr;
#pragma unroll
        for (int j = 0; j < 4; ++j)
          Ps[w][qr * 64 + (((2 * j + (l15 >> 3)) ^ (qr & 7)) * 8) + (l15 & 7)] = f2bf(p[j]);
      }
    // O += P V
#pragma unroll
    for (int kx = 0; kx < 2; ++kx) {
      bf16x8 ap[2];
#pragma unroll
      for (int i = 0; i < 2; ++i) {
        int r = i * 16 + l15;
        ap[i] = *(const bf16x8*)&Ps[w][r * 64 + (((kx * 4 + lg) ^ (r & 7)) * 8)];
      }
#pragma unroll
      for (int js = 0; js < 4; ++js) {
        int r = js * 16 + l15;
        bf16x8 bv = *(const bf16x8*)&Vt[r * 64 + (((kx * 4 + lg) ^ (r & 7)) * 8)];
#pragma unroll
        for (int i = 0; i < 2; ++i)
          o[i][js] = __builtin_amdgcn_mfma_f32_16x16x32_bf16(ap[i], bv, o[i][js], 0, 0, 0);
      }
    }
  }

  int b = bh >> 4, h = bh & 15;
#pragma unroll
  for (int i = 0; i < 2; ++i)
#pragma unroll
    for (int rr = 0; rr < 4; ++rr) {
      float inv = 1.f / lrun[i][rr];
      int tg = qb * 128 + w * 32 + i * 16 + (lg << 2) + rr;
      size_t base = ((size_t)(b * Tdim + tg)) * Edim + h * 64;
#pragma unroll
      for (int js = 0; js < 4; ++js) Ob[base + js * 16 + l15] = f2bf(o[i][js][rr] * inv);
    }
}

// ---------------------------------------------------------------------------
extern "C" void kernel_launch(void* const* d_in, const int* in_sizes, int n_in,
                              void* d_out, int out_size, void* d_ws, size_t ws_size,
                              hipStream_t stream) {
  const float* queries = (const float*)d_in[0];
  const float* keys    = (const float*)d_in[1];
  const float* values  = (const float*)d_in[2];
  const float* Wq = (const float*)d_in[3];
  const float* Wk = (const float*)d_in[4];
  const float* Wv = (const float*)d_in[5];
  const float* Wo = (const float*)d_in[6];
  const float* bo = (const float*)d_in[7];
  const float* qlnw = (const float*)d_in[8];
  const float* qlnb = (const float*)d_in[9];
  const float* klnw = (const float*)d_in[10];
  const float* klnb = (const float*)d_in[11];
  float* out = (float*)d_out;

  unsigned short* Wtq = (unsigned short*)d_ws;
  unsigned short* Wtk = Wtq + 1024 * 1024;
  unsigned short* Wtv = Wtk + 1024 * 1024;
  unsigned short* Wto = Wtv + 1024 * 1024;
  unsigned short* Qn  = Wto + 1024 * 1024;
  unsigned short* Kn  = Qn + (size_t)Mdim * Edim;
  unsigned short* Vb  = Kn + (size_t)Mdim * Edim;
  unsigned short* Ob  = Vb + (size_t)Mdim * Edim;

  wconv_k<<<dim3(32, 32, 4), dim3(32, 8), 0, stream>>>(Wq, Wk, Wv, Wo, Wtq, Wtk, Wtv, Wto);
  qkv_k<<<dim3(8, 32, 3), 256, 0, stream>>>(queries, keys, values, Wtq, Wtk, Wtv,
                                            qlnw, qlnb, klnw, klnb, Qn, Kn, Vb);
  flash_k<<<dim3(16, 32), 256, 0, stream>>>(Qn, Kn, Vb, Ob);
  gemmo_k<<<dim3(16, 32), 256, 0, stream>>>(Ob, Wto, bo, out);
}

// Round 3
// 247.214 us; speedup vs baseline: 1.5969x; 1.2283x over previous
//
#include <hip/hip_runtime.h>

#define Tdim 2048
#define Edim 1024
#define Hdim 16
#define Sdim 64
#define Mdim 4096
#define LN_EPS 1e-5f
#define QKSCALE 0.21233045007200477f  // 1024^-0.25 * sqrt(log2(e))  [log2-domain softmax]

typedef __bf16 bf16x8 __attribute__((ext_vector_type(8)));
typedef float f32x4 __attribute__((ext_vector_type(4)));

__device__ __forceinline__ unsigned short f2bf(float f) {
  union { float f; unsigned int u; } c; c.f = f;
  unsigned int u = c.u;
  return (unsigned short)((u + 0x7FFFu + ((u >> 16) & 1u)) >> 16);
}

__device__ __forceinline__ float exp2fast(float x) {
  float r;
  asm("v_exp_f32 %0, %1" : "=v"(r) : "v"(x));
  return r;
}

// async global->LDS, 16B per lane, lane-contiguous at LDS base
__device__ __forceinline__ void gl_lds16(const void* g, void* l) {
  __builtin_amdgcn_global_load_lds(
      (const __attribute__((address_space(1))) void*)g,
      (__attribute__((address_space(3))) void*)l, 16, 0, 0);
}

// pack two fp32 (as bits) -> dword of two bf16 (truncate)
__device__ __forceinline__ unsigned int pk2bf(unsigned int lo, unsigned int hi) {
  return __builtin_amdgcn_perm(hi, lo, 0x07060302u);
}

// ---------------------------------------------------------------------------
// fp32 -> bf16 convert of the three activation matrices (8 elems/thread)
// ---------------------------------------------------------------------------
__global__ __launch_bounds__(256) void cvt_k(
    const float* __restrict__ X0, const float* __restrict__ X1, const float* __restrict__ X2,
    unsigned short* __restrict__ Y0, unsigned short* __restrict__ Y1,
    unsigned short* __restrict__ Y2) {
  const float* X = blockIdx.z == 0 ? X0 : blockIdx.z == 1 ? X1 : X2;
  unsigned short* Y = blockIdx.z == 0 ? Y0 : blockIdx.z == 1 ? Y1 : Y2;
  size_t i = ((size_t)blockIdx.x * 256 + threadIdx.x) * 8;
  uint4 a = *(const uint4*)&X[i];
  uint4 b = *(const uint4*)&X[i + 4];
  uint4 o;
  o.x = pk2bf(a.x, a.y);
  o.y = pk2bf(a.z, a.w);
  o.z = pk2bf(b.x, b.y);
  o.w = pk2bf(b.z, b.w);
  *(uint4*)&Y[i] = o;
}

// ---------------------------------------------------------------------------
// Transpose + convert W [K][N] fp32 -> Wt [N][K] bf16 (4 matrices via grid.z)
// ---------------------------------------------------------------------------
__global__ __launch_bounds__(256) void wconv_k(
    const float* __restrict__ W0, const float* __restrict__ W1,
    const float* __restrict__ W2, const float* __restrict__ W3,
    unsigned short* __restrict__ O0, unsigned short* __restrict__ O1,
    unsigned short* __restrict__ O2, unsigned short* __restrict__ O3) {
  const float* W = blockIdx.z == 0 ? W0 : blockIdx.z == 1 ? W1 : blockIdx.z == 2 ? W2 : W3;
  unsigned short* O = blockIdx.z == 0 ? O0 : blockIdx.z == 1 ? O1 : blockIdx.z == 2 ? O2 : O3;
  __shared__ float tile[32][33];
  int n0 = blockIdx.x * 32, k0 = blockIdx.y * 32;
  int tx = threadIdx.x, ty = threadIdx.y;  // block (32,8)
  for (int yy = ty; yy < 32; yy += 8)
    tile[yy][tx] = W[(size_t)(k0 + yy) * Edim + n0 + tx];
  __syncthreads();
  for (int yy = ty; yy < 32; yy += 8)
    O[(size_t)(n0 + yy) * Edim + k0 + tx] = f2bf(tile[tx][yy]);
}

// ---------------------------------------------------------------------------
// Fused QKV GEMM (pure bf16): 128x128 tile, BK=64, double-buffered LDS,
// global_load_lds for both operands, 2-phase prefetch, one barrier/k-step.
// Epilogue: per-head LayerNorm * QKSCALE (z<2) / plain (z==2) -> bf16 [B,H,T,S]
// ---------------------------------------------------------------------------
__global__ __launch_bounds__(256) void qkv_k(
    const unsigned short* __restrict__ Qa, const unsigned short* __restrict__ Ka,
    const unsigned short* __restrict__ Va,
    const unsigned short* __restrict__ Bq, const unsigned short* __restrict__ Bk,
    const unsigned short* __restrict__ Bv,
    const float* __restrict__ qlnw, const float* __restrict__ qlnb,
    const float* __restrict__ klnw, const float* __restrict__ klnb,
    unsigned short* __restrict__ Oq, unsigned short* __restrict__ Ok,
    unsigned short* __restrict__ Ov) {
  __shared__ unsigned short As[2][128 * 64];
  __shared__ unsigned short Bs[2][128 * 64];
  const int z = blockIdx.z;
  const unsigned short* A = z == 0 ? Qa : z == 1 ? Ka : Va;
  const unsigned short* Bt = z == 0 ? Bq : z == 1 ? Bk : Bv;
  const float* lnw = z == 0 ? qlnw : klnw;
  const float* lnb = z == 0 ? qlnb : klnb;
  unsigned short* obf = z == 0 ? Oq : z == 1 ? Ok : Ov;
  const bool doLN = z < 2;

  int tid = threadIdx.x, lane = tid & 63, w = tid >> 6;
  int wr = w >> 1, wc = w & 1;
  int lg = lane >> 4, l15 = lane & 15;
  int lr = lane >> 3, ls = lane & 7;
  int m0 = blockIdx.y * 128, n0 = blockIdx.x * 128;

  f32x4 acc[4][4];
#pragma unroll
  for (int i = 0; i < 4; ++i)
#pragma unroll
    for (int j = 0; j < 4; ++j) acc[i][j] = f32x4{0.f, 0.f, 0.f, 0.f};

  auto stage = [&](int buf, int ks) {
    int k0 = ks * 64;
#pragma unroll
    for (int q = 0; q < 4; ++q) {
      int c = w * 4 + q, r = c * 8 + lr;
      gl_lds16(&A[(size_t)(m0 + r) * Edim + k0 + ((ls ^ (r & 7)) * 8)], &As[buf][c * 512]);
    }
#pragma unroll
    for (int q = 0; q < 4; ++q) {
      int c = w * 4 + q, r = c * 8 + lr;
      gl_lds16(&Bt[(size_t)(n0 + r) * Edim + k0 + ((ls ^ (r & 7)) * 8)], &Bs[buf][c * 512]);
    }
  };

  stage(0, 0);
  for (int ks = 0; ks < 16; ++ks) {
    int cur = ks & 1;
    __syncthreads();  // drains staged loads into [cur]; gates reuse of [cur^1]
    if (ks + 1 < 16) stage(cur ^ 1, ks + 1);
    __builtin_amdgcn_s_setprio(1);
#pragma unroll
    for (int kx = 0; kx < 2; ++kx) {
      bf16x8 a[4], bb[4];
#pragma unroll
      for (int i = 0; i < 4; ++i) {
        int r = wr * 64 + i * 16 + l15;
        a[i] = *(const bf16x8*)&As[cur][r * 64 + (((kx * 4 + lg) ^ (r & 7)) * 8)];
      }
#pragma unroll
      for (int j = 0; j < 4; ++j) {
        int r = wc * 64 + j * 16 + l15;
        bb[j] = *(const bf16x8*)&Bs[cur][r * 64 + (((kx * 4 + lg) ^ (r & 7)) * 8)];
      }
#pragma unroll
      for (int i = 0; i < 4; ++i)
#pragma unroll
        for (int j = 0; j < 4; ++j)
          acc[i][j] = __builtin_amdgcn_mfma_f32_16x16x32_bf16(a[i], bb[j], acc[i][j], 0, 0, 0);
    }
    __builtin_amdgcn_s_setprio(0);
  }

  int mb = m0 + wr * 64;
  int h = (n0 >> 6) + wc;  // wave's 64 cols == one head
#pragma unroll
  for (int i = 0; i < 4; ++i) {
#pragma unroll
    for (int r = 0; r < 4; ++r) {
      float xv[4];
#pragma unroll
      for (int j = 0; j < 4; ++j) xv[j] = acc[i][j][r];
      float outv[4];
      if (doLN) {
        float sum = xv[0] + xv[1] + xv[2] + xv[3];
        float sq = xv[0] * xv[0] + xv[1] * xv[1] + xv[2] * xv[2] + xv[3] * xv[3];
#pragma unroll
        for (int off = 1; off < 16; off <<= 1) {
          sum += __shfl_xor(sum, off);
          sq += __shfl_xor(sq, off);
        }
        float mean = sum * (1.f / 64.f);
        float var = sq * (1.f / 64.f) - mean * mean;
        float rstd = rsqrtf(var + LN_EPS);
#pragma unroll
        for (int j = 0; j < 4; ++j) {
          int s = j * 16 + l15;
          outv[j] = ((xv[j] - mean) * rstd * lnw[s] + lnb[s]) * QKSCALE;
        }
      } else {
#pragma unroll
        for (int j = 0; j < 4; ++j) outv[j] = xv[j];
      }
      int m = mb + i * 16 + (lg << 2) + r;
      int bb2 = m >> 11, tt = m & 2047;
      size_t base = ((size_t)(bb2 * Hdim + h) * Tdim + tt) * Sdim;
#pragma unroll
      for (int j = 0; j < 4; ++j) obf[base + j * 16 + l15] = f2bf(outv[j]);
    }
  }
}

// ---------------------------------------------------------------------------
// Out-projection GEMM: Y = Ob(bf16) * Wto^T + bo -> fp32. 128x64 tile, BK=64,
// double-buffered + prefetch (same schedule as qkv_k).
// ---------------------------------------------------------------------------
__global__ __launch_bounds__(256) void gemmo_k(
    const unsigned short* __restrict__ A, const unsigned short* __restrict__ Bt,
    const float* __restrict__ bias, float* __restrict__ ofp) {
  __shared__ unsigned short As[2][128 * 64];
  __shared__ unsigned short Bs[2][64 * 64];
  int tid = threadIdx.x, lane = tid & 63, w = tid >> 6;
  int wr = w >> 1, wc = w & 1;
  int lg = lane >> 4, l15 = lane & 15;
  int lr = lane >> 3, ls = lane & 7;
  int m0 = blockIdx.y * 128, n0 = blockIdx.x * 64;

  f32x4 acc[4][2];
#pragma unroll
  for (int i = 0; i < 4; ++i)
#pragma unroll
    for (int j = 0; j < 2; ++j) acc[i][j] = f32x4{0.f, 0.f, 0.f, 0.f};

  auto stage = [&](int buf, int ks) {
    int k0 = ks * 64;
#pragma unroll
    for (int q = 0; q < 4; ++q) {
      int c = w * 4 + q, r = c * 8 + lr;
      gl_lds16(&A[(size_t)(m0 + r) * Edim + k0 + ((ls ^ (r & 7)) * 8)], &As[buf][c * 512]);
    }
#pragma unroll
    for (int q = 0; q < 2; ++q) {
      int c = w * 2 + q, r = c * 8 + lr;
      gl_lds16(&Bt[(size_t)(n0 + r) * Edim + k0 + ((ls ^ (r & 7)) * 8)], &Bs[buf][c * 512]);
    }
  };

  stage(0, 0);
  for (int ks = 0; ks < 16; ++ks) {
    int cur = ks & 1;
    __syncthreads();
    if (ks + 1 < 16) stage(cur ^ 1, ks + 1);
    __builtin_amdgcn_s_setprio(1);
#pragma unroll
    for (int kx = 0; kx < 2; ++kx) {
      bf16x8 a[4], bb[2];
#pragma unroll
      for (int i = 0; i < 4; ++i) {
        int r = wr * 64 + i * 16 + l15;
        a[i] = *(const bf16x8*)&As[cur][r * 64 + (((kx * 4 + lg) ^ (r & 7)) * 8)];
      }
#pragma unroll
      for (int j = 0; j < 2; ++j) {
        int r = wc * 32 + j * 16 + l15;
        bb[j] = *(const bf16x8*)&Bs[cur][r * 64 + (((kx * 4 + lg) ^ (r & 7)) * 8)];
      }
#pragma unroll
      for (int i = 0; i < 4; ++i)
#pragma unroll
        for (int j = 0; j < 2; ++j)
          acc[i][j] = __builtin_amdgcn_mfma_f32_16x16x32_bf16(a[i], bb[j], acc[i][j], 0, 0, 0);
    }
    __builtin_amdgcn_s_setprio(0);
  }

  int mb = m0 + wr * 64, nb = n0 + wc * 32;
#pragma unroll
  for (int i = 0; i < 4; ++i)
#pragma unroll
    for (int r = 0; r < 4; ++r) {
      int m = mb + i * 16 + (lg << 2) + r;
#pragma unroll
      for (int j = 0; j < 2; ++j) {
        int n = nb + j * 16 + l15;
        ofp[(size_t)m * Edim + n] = acc[i][j][r] + bias[n];
      }
    }
}

// ---------------------------------------------------------------------------
// Flash attention, log2-domain. 4 waves x 16 q-rows (QBLK=64), KVBLK=64.
// Pair-fold: block handles q-segments x and 31-x -> all blocks 33 tiles.
// Double-buffered K (global_load_lds) + V (reg-staged, kv'-permuted), one
// barrier per tile. P kept per-wave, written as ds_write_b64.
// kv' = (kv&15)*4 + (kv>>4); V staged with the same permutation so the MFMA
// contraction over k is permutation-invariant.
// ---------------------------------------------------------------------------
__global__ __launch_bounds__(256) void flash_k(
    const unsigned short* __restrict__ Qn, const unsigned short* __restrict__ Kn,
    const unsigned short* __restrict__ Vb, unsigned short* __restrict__ Ob) {
  __shared__ unsigned short Qs[64 * 64];
  __shared__ unsigned short Ks[2][64 * 64];
  __shared__ unsigned short Vt[2][64 * 64];
  __shared__ unsigned short Ps[4][16 * 64];

  // bijective XCD swizzle: 512 = 8 XCDs x 64; same-bh blocks share an XCD
  int wid0 = blockIdx.y * gridDim.x + blockIdx.x;
  int wid = (wid0 & 7) * 64 + (wid0 >> 3);
  int x = wid & 15, bh = wid >> 4;

  int tid = threadIdx.x, lane = tid & 63, w = tid >> 6;
  int lg = lane >> 4, l15 = lane & 15;
  int lr = lane >> 3, ls = lane & 7;
  int vl = tid >> 4, vs0 = (tid & 15) * 4;
  const unsigned short* Kg = Kn + (size_t)bh * Tdim * Sdim;
  const unsigned short* Vg = Vb + (size_t)bh * Tdim * Sdim;
  int b = bh >> 4, h = bh & 15;

  uint2 vreg[4];
  auto ldV = [&](int t) {
    const unsigned short* p = Vg + (size_t)t * 64 * 64;
#pragma unroll
    for (int j = 0; j < 4; ++j) vreg[j] = *(const uint2*)&p[(j * 16 + vl) * 64 + vs0];
  };
  auto stV = [&](unsigned short* dst) {
#pragma unroll
    for (int st = 0; st < 4; ++st) {
      int s = vs0 + st;
      unsigned int e[4];
#pragma unroll
      for (int j = 0; j < 4; ++j) {
        unsigned int wrd = (st & 2) ? vreg[j].y : vreg[j].x;
        e[j] = (st & 1) ? (wrd >> 16) : (wrd & 0xffffu);
      }
      uint2 wv;
      wv.x = e[0] | (e[1] << 16);
      wv.y = e[2] | (e[3] << 16);
      *(uint2*)((char*)dst + s * 128 + (((vl >> 1) ^ (s & 7)) * 16) + (vl & 1) * 8) = wv;
    }
  };

  for (int ph = 0; ph < 2; ++ph) {
    int qseg = ph ? (31 - x) : x;
    const unsigned short* Qg = Qn + ((size_t)bh * Tdim + (size_t)qseg * 64) * Sdim;
    int nt = qseg + 1;

    // prologue: stage Q + K0 (async), V0 via regs
#pragma unroll
    for (int q = 0; q < 2; ++q) {
      int c = w * 2 + q, r = c * 8 + lr;
      gl_lds16(&Qg[(size_t)r * 64 + ((ls ^ (r & 7)) * 8)], &Qs[c * 512]);
      gl_lds16(&Kg[(size_t)r * 64 + ((ls ^ (r & 7)) * 8)], &Ks[0][c * 512]);
    }
    ldV(0);
    stV(&Vt[0][0]);

    f32x4 sf[4], o[4];
    float mrun[4], lrun[4];
#pragma unroll
    for (int r = 0; r < 4; ++r) {
      mrun[r] = -1e30f;
      lrun[r] = 0.f;
      o[r] = f32x4{0.f, 0.f, 0.f, 0.f};
    }
    __syncthreads();

    for (int t = 0; t < nt; ++t) {
      int cur = t & 1;
      if (t + 1 < nt) {  // prefetch next tile (overlaps this tile's compute)
#pragma unroll
        for (int q = 0; q < 2; ++q) {
          int c = w * 2 + q, r = c * 8 + lr;
          gl_lds16(&Kg[((size_t)(t + 1) * 64 + r) * 64 + ((ls ^ (r & 7)) * 8)],
                   &Ks[cur ^ 1][c * 512]);
        }
        ldV(t + 1);
      }
      // S = Q K^T  (log2-domain scores; scale folded into Q,K)
#pragma unroll
      for (int j = 0; j < 4; ++j) sf[j] = f32x4{0.f, 0.f, 0.f, 0.f};
      __builtin_amdgcn_s_setprio(1);
#pragma unroll
      for (int kx = 0; kx < 2; ++kx) {
        int rq = w * 16 + l15;
        bf16x8 aq = *(const bf16x8*)&Qs[rq * 64 + (((kx * 4 + lg) ^ (rq & 7)) * 8)];
#pragma unroll
        for (int j = 0; j < 4; ++j) {
          int rk = j * 16 + l15;
          bf16x8 bk = *(const bf16x8*)&Ks[cur][rk * 64 + (((kx * 4 + lg) ^ (rk & 7)) * 8)];
          sf[j] = __builtin_amdgcn_mfma_f32_16x16x32_bf16(aq, bk, sf[j], 0, 0, 0);
        }
      }
      __builtin_amdgcn_s_setprio(0);
      if (t == qseg) {  // causal diag tile
#pragma unroll
        for (int j = 0; j < 4; ++j)
#pragma unroll
          for (int rr = 0; rr < 4; ++rr)
            if (j * 16 + l15 > w * 16 + (lg << 2) + rr) sf[j][rr] = -1e30f;
      }
      // row max (16-lane groups hold one row's 64 cols)
      float mx[4];
#pragma unroll
      for (int rr = 0; rr < 4; ++rr) {
        float m0v = fmaxf(fmaxf(sf[0][rr], sf[1][rr]), fmaxf(sf[2][rr], sf[3][rr]));
#pragma unroll
        for (int off = 1; off < 16; off <<= 1) m0v = fmaxf(m0v, __shfl_xor(m0v, off));
        mx[rr] = m0v;
      }
      // defer-max: skip rescale when growth <= 8 (p bounded by 2^8)
      int fastok = (mx[0] <= mrun[0] + 8.f) && (mx[1] <= mrun[1] + 8.f) &&
                   (mx[2] <= mrun[2] + 8.f) && (mx[3] <= mrun[3] + 8.f);
      if (!__all(fastok)) {
#pragma unroll
        for (int rr = 0; rr < 4; ++rr) {
          float mnew = fmaxf(mrun[rr], mx[rr]);
          float alpha = exp2fast(mrun[rr] - mnew);
          mrun[rr] = mnew;
          lrun[rr] *= alpha;
#pragma unroll
          for (int js = 0; js < 4; ++js) o[js][rr] *= alpha;
        }
      }
      // p = 2^(s-m); deferred l-sum (per-lane partial, reduced at end)
#pragma unroll
      for (int rr = 0; rr < 4; ++rr) {
        float p0 = exp2fast(sf[0][rr] - mrun[rr]);
        float p1 = exp2fast(sf[1][rr] - mrun[rr]);
        float p2 = exp2fast(sf[2][rr] - mrun[rr]);
        float p3 = exp2fast(sf[3][rr] - mrun[rr]);
        lrun[rr] += (p0 + p1) + (p2 + p3);
        union { float f; unsigned int u; } c0{p0}, c1{p1}, c2{p2}, c3{p3};
        uint2 wv;
        wv.x = pk2bf(c0.u, c1.u);
        wv.y = pk2bf(c2.u, c3.u);
        int qr = (lg << 2) + rr;
        *(uint2*)((char*)&Ps[w][0] + qr * 128 + (((l15 >> 1) ^ (qr & 7)) * 16) +
                  (l15 & 1) * 8) = wv;
      }
      // O += P V   (kv'-permuted k-dim on both operands)
      __builtin_amdgcn_s_setprio(1);
#pragma unroll
      for (int kx = 0; kx < 2; ++kx) {
        bf16x8 ap = *(const bf16x8*)((char*)&Ps[w][0] + l15 * 128 +
                                     (((kx * 4 + lg) ^ (l15 & 7)) * 16));
#pragma unroll
        for (int js = 0; js < 4; ++js) {
          int rv = js * 16 + l15;
          bf16x8 bv = *(const bf16x8*)((char*)&Vt[cur][0] + rv * 128 +
                                       (((kx * 4 + lg) ^ (rv & 7)) * 16));
          o[js] = __builtin_amdgcn_mfma_f32_16x16x32_bf16(ap, bv, o[js], 0, 0, 0);
        }
      }
      __builtin_amdgcn_s_setprio(0);
      if (t + 1 < nt) stV(&Vt[cur ^ 1][0]);
      __syncthreads();  // single barrier per tile
    }

    // epilogue: reduce deferred l, normalize, store
#pragma unroll
    for (int rr = 0; rr < 4; ++rr) {
      float l = lrun[rr];
#pragma unroll
      for (int off = 1; off < 16; off <<= 1) l += __shfl_xor(l, off);
      float inv = 1.f / l;
      int tg = qseg * 64 + w * 16 + (lg << 2) + rr;
      size_t base = ((size_t)b * Tdim + tg) * Edim + h * 64;
#pragma unroll
      for (int js = 0; js < 4; ++js) Ob[base + js * 16 + l15] = f2bf(o[js][rr] * inv);
    }
  }
}

// ---------------------------------------------------------------------------
extern "C" void kernel_launch(void* const* d_in, const int* in_sizes, int n_in,
                              void* d_out, int out_size, void* d_ws, size_t ws_size,
                              hipStream_t stream) {
  const float* queries = (const float*)d_in[0];
  const float* keys    = (const float*)d_in[1];
  const float* values  = (const float*)d_in[2];
  const float* Wq = (const float*)d_in[3];
  const float* Wk = (const float*)d_in[4];
  const float* Wv = (const float*)d_in[5];
  const float* Wo = (const float*)d_in[6];
  const float* bo = (const float*)d_in[7];
  const float* qlnw = (const float*)d_in[8];
  const float* qlnb = (const float*)d_in[9];
  const float* klnw = (const float*)d_in[10];
  const float* klnb = (const float*)d_in[11];
  float* out = (float*)d_out;

  unsigned short* Wtq = (unsigned short*)d_ws;          // 4 x 2MB
  unsigned short* Wtk = Wtq + 1024 * 1024;
  unsigned short* Wtv = Wtk + 1024 * 1024;
  unsigned short* Wto = Wtv + 1024 * 1024;
  unsigned short* Qn  = Wto + 1024 * 1024;              // 3 x 8MB
  unsigned short* Kn  = Qn + (size_t)Mdim * Edim;
  unsigned short* Vb  = Kn + (size_t)Mdim * Edim;
  unsigned short* Qa  = Vb + (size_t)Mdim * Edim;       // 3 x 8MB (bf16 activations)
  unsigned short* Ka  = Qa + (size_t)Mdim * Edim;
  unsigned short* Va  = Ka + (size_t)Mdim * Edim;
  unsigned short* Ob  = Qa;                             // alias: Qa dead after qkv_k

  cvt_k<<<dim3(2048, 1, 3), 256, 0, stream>>>(queries, keys, values, Qa, Ka, Va);
  wconv_k<<<dim3(32, 32, 4), dim3(32, 8), 0, stream>>>(Wq, Wk, Wv, Wo, Wtq, Wtk, Wtv, Wto);
  qkv_k<<<dim3(8, 32, 3), 256, 0, stream>>>(Qa, Ka, Va, Wtq, Wtk, Wtv,
                                            qlnw, qlnb, klnw, klnb, Qn, Kn, Vb);
  flash_k<<<dim3(16, 32), 256, 0, stream>>>(Qn, Kn, Vb, Ob);
  gemmo_k<<<dim3(16, 32), 256, 0, stream>>>(Ob, Wto, bo, out);
}